// Round 16
// baseline (805.197 us; speedup 1.0000x reference)
//
#include <hip/hip_runtime.h>
#include <math.h>

#define DD 128
typedef unsigned short ushort_t;
typedef unsigned int uint_t;
typedef __attribute__((ext_vector_type(8))) short bf16x8;
typedef __attribute__((ext_vector_type(4))) float f32x4;

// ---------------- DPP / bf16 helpers -------------------
template<int CTRL>
__device__ __forceinline__ float dppAdd(float x) {
    int y = __builtin_amdgcn_update_dpp(0, __float_as_int(x), CTRL, 0xF, 0xF, true);
    return x + __int_as_float(y);
}
__device__ __forceinline__ float red16(float x) {
    x = dppAdd<0xB1>(x);   // quad_perm xor1
    x = dppAdd<0x4E>(x);   // quad_perm xor2
    x = dppAdd<0x141>(x);  // row_half_mirror
    x = dppAdd<0x140>(x);  // row_mirror
    return x;
}

__device__ __forceinline__ ushort_t f2bf(float f) {
    uint_t u = __float_as_uint(f);
    u += 0x7FFFu + ((u >> 16) & 1u);
    return (ushort_t)(u >> 16);
}
__device__ __forceinline__ uint_t packbf(float a, float b) {
    return (uint_t)f2bf(a) | ((uint_t)f2bf(b) << 16);
}
__device__ __forceinline__ float bflo(uint_t u) { return __uint_as_float(u << 16); }
__device__ __forceinline__ float bfhi(uint_t u) { return __uint_as_float(u & 0xFFFF0000u); }

#define NA_STRIDE 160   // words/node: 64 (wv bf16) + 96 (sea bf16)

// ======================= CSR build (once per call) =======================
__global__ __launch_bounds__(256) void hist_kernel(const int* __restrict__ ei,
                                                   int* __restrict__ cnt, int E) {
    int i = blockIdx.x * 256 + threadIdx.x;
    if (i < E) atomicAdd(&cnt[ei[E + i]], 1);
}

__global__ __launch_bounds__(1024) void scan_kernel(const int* __restrict__ cnt,
                                                    int* __restrict__ row_start,
                                                    int* __restrict__ cursor, int N) {
    __shared__ int part[1024];
    const int tid = threadIdx.x;
    const int chunk = (N + 1023) >> 10;
    const int lo = min(N, tid * chunk);
    const int hi = min(N, lo + chunk);
    int s = 0;
    for (int i = lo; i < hi; ++i) s += cnt[i];
    part[tid] = s;
    __syncthreads();
    for (int off = 1; off < 1024; off <<= 1) {
        int val = 0;
        if (tid >= off) val = part[tid - off];
        __syncthreads();
        part[tid] += val;
        __syncthreads();
    }
    int run = (tid == 0) ? 0 : part[tid - 1];
    for (int i = lo; i < hi; ++i) {
        row_start[i] = run; cursor[i] = run;
        run += cnt[i];
    }
    if (tid == 1023) row_start[N] = part[1023];
}

// meta scatter: one int4 record per edge (src, eid, rel_bits, 0)
__global__ __launch_bounds__(256) void scatter_fb_kernel(
    const int* __restrict__ ei, const float* __restrict__ lu, const float* __restrict__ t,
    int* __restrict__ cursor, int4* __restrict__ ser, int E)
{
    int i = blockIdx.x * 256 + threadIdx.x;
    if (i < E) {
        int s = ei[i], d = ei[E + i];
        int pos = atomicAdd(&cursor[d], 1);
        ser[pos] = make_int4(s, i, __float_as_int(lu[s] - t[i]), 0);
    }
}

// fused streaming f32 -> bf16 for msg (n1 float4s) and x (n2 float4s)
__global__ __launch_bounds__(256) void tobf_kernel(
    const float4* __restrict__ a4, uint2* __restrict__ oa, size_t n1,
    const float4* __restrict__ b4, uint2* __restrict__ ob, size_t n2)
{
    size_t i = (size_t)blockIdx.x * 256 + threadIdx.x;
    const size_t stride = (size_t)gridDim.x * 256;
    const size_t total = n1 + n2;
    for (; i < total; i += stride) {
        if (i < n1) {
            float4 v = a4[i];
            oa[i] = make_uint2(packbf(v.x, v.y), packbf(v.z, v.w));
        } else {
            size_t j = i - n1;
            float4 v = b4[j];
            ob[j] = make_uint2(packbf(v.x, v.y), packbf(v.z, v.w));
        }
    }
}

// ====== pack 6 weight mats x 2 layers -> bf16 Wcat_t[2][768][128] ========
// blockIdx.y = layer. which 0..3: copy Wq/Wk/Wv/Wsk; 4/5: Wu=Wq@B inline.
__global__ __launch_bounds__(256) void pack_w_kernel(
    const float* __restrict__ Wq1, const float* __restrict__ Wk1,
    const float* __restrict__ Wv1, const float* __restrict__ Wsk1,
    const float* __restrict__ We1,
    const float* __restrict__ bq1, const float* __restrict__ bk1,
    const float* __restrict__ bv1, const float* __restrict__ bsk1,
    const float* __restrict__ Wq2, const float* __restrict__ Wk2,
    const float* __restrict__ Wv2, const float* __restrict__ Wsk2,
    const float* __restrict__ We2,
    const float* __restrict__ bq2, const float* __restrict__ bk2,
    const float* __restrict__ bv2, const float* __restrict__ bsk2,
    ushort_t* __restrict__ wcat, float* __restrict__ bcat)
{
    const int layer = blockIdx.y;
    const float *Wq, *Wk, *Wv, *Wsk, *We, *bq, *bk, *bv, *bsk;
    if (layer == 0) { Wq=Wq1; Wk=Wk1; Wv=Wv1; Wsk=Wsk1; We=We1; bq=bq1; bk=bk1; bv=bv1; bsk=bsk1; }
    else            { Wq=Wq2; Wk=Wk2; Wv=Wv2; Wsk=Wsk2; We=We2; bq=bq2; bk=bk2; bv=bv2; bsk=bsk2; }

    int idx = blockIdx.x * 256 + threadIdx.x;   // [0, 98304)
    int cg = idx >> 7, k = idx & 127;
    int which = cg >> 7, col = cg & 127;
    float v = 0.f, b = 0.f;
    if (which < 4) {
        switch (which) {
            case 0:  v = Wq[k * 128 + col];  b = bq[col];  break;
            case 1:  v = Wk[k * 128 + col];  b = bk[col];  break;
            case 2:  v = Wv[k * 128 + col];  b = bv[col];  break;
            default: v = Wsk[k * 128 + col]; b = bsk[col]; break;
        }
    } else {
        const int h = which - 4;
        const int lh = col >> 3, j = col & 7;
        const int row = (j < 2) ? (2 * lh + j) : (j < 6 ? (32 + 4 * lh + (j - 2)) : -1);
        if (row >= 0) {
            const float* Wer = We + row * 128 + h * 64;
            const float* Wqr = Wq + k * 128 + h * 64;
            #pragma unroll 8
            for (int c = 0; c < 64; ++c) v += Wqr[c] * Wer[c];
            if (k == 0) {
                const float* bqr = bq + h * 64;
                #pragma unroll 8
                for (int c = 0; c < 64; ++c) b += bqr[c] * Wer[c];
            }
        }
    }
    wcat[(size_t)layer * 98304 + cg * 128 + k] = f2bf(v);
    if (k == 0) bcat[layer * 768 + cg] = b;
}

// ======================= MFMA 6-way node GEMM (bf16 in, K=128) ===========
// cb: 0=q(bf16) 1=k(bf16) 2=v(bf16) 3=skip(f32) 4=u0(bf16) 5=u1(bf16)
__global__ __launch_bounds__(256) void mfma_gemm_kernel(
    const uint4* __restrict__ xb4,   // [M][16] uint4 (128 bf16/row)
    const uint4* __restrict__ wc4,   // [768][16]
    const float* __restrict__ bcat,  // [768]
    ushort_t* __restrict__ qbB, ushort_t* __restrict__ kvbS,
    float* __restrict__ sb, ushort_t* __restrict__ ubB, int M)
{
    __shared__ ushort_t Xs[64 * 136];
    __shared__ ushort_t Wt[128 * 136];
    const int tid = threadIdx.x;
    const int m0 = blockIdx.x * 64;
    const int cb = blockIdx.y;

    #pragma unroll
    for (int i = 0; i < 4; ++i) {
        int f = tid + i * 256, r = f >> 4, ch = f & 15;
        uint4 val = make_uint4(0, 0, 0, 0);
        if (m0 + r < M) val = xb4[(size_t)(m0 + r) * 16 + ch];
        *(uint4*)&Xs[r * 136 + ch * 8] = val;
    }
    #pragma unroll
    for (int i = 0; i < 8; ++i) {
        int f = tid + i * 256, r = f >> 4, ch = f & 15;
        *(uint4*)&Wt[r * 136 + ch * 8] = wc4[(size_t)(cb * 128 + r) * 16 + ch];
    }
    __syncthreads();

    const int w = tid >> 6, l = tid & 63, rl = l & 15, g = l >> 4;
    f32x4 acc[8];
    #pragma unroll
    for (int c = 0; c < 8; ++c) acc[c] = (f32x4){0.f, 0.f, 0.f, 0.f};
    const ushort_t* Ar = &Xs[(w * 16 + rl) * 136];
    #pragma unroll
    for (int kk = 0; kk < 4; ++kk) {
        bf16x8 a = *(const bf16x8*)&Ar[kk * 32 + g * 8];
        #pragma unroll
        for (int c = 0; c < 8; ++c) {
            bf16x8 b = *(const bf16x8*)&Wt[(c * 16 + rl) * 136 + kk * 32 + g * 8];
            acc[c] = __builtin_amdgcn_mfma_f32_16x16x32_bf16(a, b, acc[c], 0, 0, 0);
        }
    }
    float bias_c[8];
    #pragma unroll
    for (int c = 0; c < 8; ++c) bias_c[c] = bcat[cb * 128 + c * 16 + rl];

    ushort_t* bp = nullptr; int bstride = 0, boff = 0;
    switch (cb) {
        case 0: bp = qbB;  bstride = 128; boff = 0;   break;
        case 1: bp = kvbS; bstride = 256; boff = 0;   break;
        case 2: bp = kvbS; bstride = 256; boff = 128; break;
        case 4: bp = ubB;  bstride = 256; boff = 0;   break;
        case 5: bp = ubB;  bstride = 256; boff = 128; break;
        default: break;  // cb==3 -> f32 skip
    }
    const int R0 = m0 + w * 16 + g * 4;
    #pragma unroll
    for (int r = 0; r < 4; ++r) {
        int R = R0 + r;
        if (R < M) {
            if (cb == 3) {
                #pragma unroll
                for (int c = 0; c < 8; ++c)
                    sb[(size_t)R * 128 + c * 16 + rl] = acc[c][r] + bias_c[c];
            } else {
                #pragma unroll
                for (int c = 0; c < 8; ++c)
                    bp[(size_t)R * bstride + boff + c * 16 + rl] = f2bf(acc[c][r] + bias_c[c]);
            }
        }
    }
}

// ======================= node-centric attention ==========================
// Two-chunk pipeline; gather(nxt) issued mid-PROCESS(cur) so it gets ~half a
// PROCESS of latency cover at unchanged register pressure.
template<int PRE>
__global__ __launch_bounds__(256) void node_attn_kernel(
    const int* __restrict__ row_start, const int4* __restrict__ ser,
    const uint_t* __restrict__ eaB,
    const float* __restrict__ msg,
    const float* __restrict__ time_w, const float* __restrict__ time_b,
    const ushort_t* __restrict__ qbB, const uint_t* __restrict__ kvb,
    const ushort_t* __restrict__ ubB, uint_t* __restrict__ nodeAccB,
    float* __restrict__ denb, int N)
{
    const int tid = threadIdx.x;
    const int g = tid >> 5, l = tid & 31;
    const int lh = l & 15;
    const int h = l >> 4;
    const int n = blockIdx.x * 8 + g;
    if (n >= N) return;

    const float twA = time_w[2 * lh], twB = time_w[2 * lh + 1];
    const float tbA = time_b[2 * lh], tbB = time_b[2 * lh + 1];
    const int e0 = row_start[n], e1 = row_start[n + 1];
    const uint2 qa = ((const uint2*)qbB)[(size_t)n * 32 + l];
    const float qx = bflo(qa.x), qy = bfhi(qa.x);
    const float qz = bflo(qa.y), qw = bfhi(qa.y);
    const uint4 ua = ((const uint4*)ubB)[(size_t)n * 32 + h * 16 + lh];
    const float uu0 = bflo(ua.x), uu1 = bfhi(ua.x);
    const float uu2 = bflo(ua.y), uu3 = bfhi(ua.y);
    const float uu4 = bflo(ua.z), uu5 = bfhi(ua.z);
    const uint2* KV2 = (const uint2*)kvb;
    const uint2* EB2 = (const uint2*)eaB;

    float4 wv = {0, 0, 0, 0};
    float sA = 0, sB = 0, s0 = 0, s1 = 0, s2 = 0, s3 = 0, denA = 0;

    struct Ch { int src[4]; float rel[4]; uint2 eb[4]; float4 mf[4]; uint2 kk[4]; uint2 vv[4]; };
    Ch cur, nxt;

    auto LOAD_META = [&](Ch& c, int b) {
        #pragma unroll
        for (int j = 0; j < 4; ++j) {
            int idx = b + j; idx = idx < e1 ? idx : e1 - 1;
            int4 m = ser[idx];
            c.src[j] = m.x;
            c.rel[j] = __int_as_float(m.z);
            if (PRE) c.eb[j] = EB2[(size_t)m.y * 16 + lh];
            else     c.mf[j] = ((const float4*)msg)[(size_t)m.y * 16 + lh];
        }
    };
    auto LOAD_GATHER = [&](Ch& c) {
        #pragma unroll
        for (int j = 0; j < 4; ++j) {
            c.kk[j] = KV2[(size_t)c.src[j] * 64 + l];
            c.vv[j] = KV2[(size_t)c.src[j] * 64 + 32 + l];
        }
    };
    auto PROC2 = [&](Ch& c, int b, int j0) {
        #pragma unroll
        for (int jj = 0; jj < 2; ++jj) {
            const int j = j0 + jj;
            float cA = __cosf(c.rel[j] * twA + tbA);
            float cB = __cosf(c.rel[j] * twB + tbB);
            float m0, m1, m2, m3;
            if (PRE) {
                m0 = bflo(c.eb[j].x); m1 = bfhi(c.eb[j].x);
                m2 = bflo(c.eb[j].y); m3 = bfhi(c.eb[j].y);
            } else {
                m0 = c.mf[j].x; m1 = c.mf[j].y; m2 = c.mf[j].z; m3 = c.mf[j].w;
            }
            float k0 = bflo(c.kk[j].x), k1 = bfhi(c.kk[j].x);
            float k2 = bflo(c.kk[j].y), k3 = bfhi(c.kk[j].y);
            float p = qx * k0 + qy * k1 + qz * k2 + qw * k3
                    + cA * uu0 + cB * uu1 + m0 * uu2 + m1 * uu3
                    + m2 * uu4 + m3 * uu5;
            p = red16(p);
            float w = __expf(p * 0.125f);
            if (b + j >= e1) w = 0.f;
            denA += w;
            float v0 = bflo(c.vv[j].x), v1 = bfhi(c.vv[j].x);
            float v2 = bflo(c.vv[j].y), v3 = bfhi(c.vv[j].y);
            wv.x += w * v0; wv.y += w * v1; wv.z += w * v2; wv.w += w * v3;
            sA += w * cA; sB += w * cB;
            s0 += w * m0; s1 += w * m1; s2 += w * m2; s3 += w * m3;
        }
    };

    if (e0 < e1) {
        LOAD_META(cur, e0);
        LOAD_GATHER(cur);
        for (int base = e0; base < e1; base += 4) {
            const bool more = (base + 4) < e1;
            if (more) LOAD_META(nxt, base + 4);
            PROC2(cur, base, 0);
            if (more) LOAD_GATHER(nxt);   // issued mid-PROCESS: covered by PROC2 below
            PROC2(cur, base, 2);
            if (more) cur = nxt;
        }
    }
    uint_t* NB = nodeAccB + (size_t)n * NA_STRIDE;
    NB[2 * l]     = packbf(wv.x, wv.y);
    NB[2 * l + 1] = packbf(wv.z, wv.w);
    NB[64 + 3 * l]     = packbf(sA, sB);
    NB[64 + 3 * l + 1] = packbf(s0, s1);
    NB[64 + 3 * l + 2] = packbf(s2, s3);
    if (lh == 0) denb[(size_t)n * 2 + h] = denA;
}

// ======================= node finish: out = (wv + sea@We)/den + skip =====
__global__ __launch_bounds__(256) void ef_finish_kernel(
    const uint_t* __restrict__ nodeAccB, const float* __restrict__ denb,
    const float* __restrict__ We,
    const float* __restrict__ sbuf, float* __restrict__ outp,
    float* __restrict__ bn_sum, float* __restrict__ bn_ssq, int N, int do_bn)
{
    __shared__ float seaL[16][2][100];
    __shared__ float red[4][16][16];
    const int tid = threadIdx.x;
    const int n0 = blockIdx.x * 16;

    #pragma unroll
    for (int it = 0; it < 6; ++it) {
        int f = tid + it * 256;
        int i2 = f / 96, wi = f - i2 * 96;
        if (n0 + i2 < N) {
            uint_t uv = nodeAccB[(size_t)(n0 + i2) * NA_STRIDE + 64 + wi];
            int L = wi / 3, k = wi - L * 3;
            int h2 = L >> 4, lh2 = L & 15;
            float lo = bflo(uv), hi = bfhi(uv);
            if (k == 0)      { seaL[i2][h2][2 * lh2] = lo;         seaL[i2][h2][2 * lh2 + 1] = hi; }
            else if (k == 1) { seaL[i2][h2][32 + 4 * lh2] = lo;    seaL[i2][h2][32 + 4 * lh2 + 1] = hi; }
            else             { seaL[i2][h2][32 + 4 * lh2 + 2] = lo; seaL[i2][h2][32 + 4 * lh2 + 3] = hi; }
        }
    }
    __syncthreads();

    const int i = tid >> 4, p = tid & 15, h = p >> 3;
    const int n = n0 + i;
    const float4* We4 = (const float4*)We;
    float a[8] = {0, 0, 0, 0, 0, 0, 0, 0};
    if (n < N) {
        uint4 wu = *(const uint4*)&nodeAccB[(size_t)n * NA_STRIDE + 4 * p];
        a[0] = bflo(wu.x); a[1] = bfhi(wu.x); a[2] = bflo(wu.y); a[3] = bfhi(wu.y);
        a[4] = bflo(wu.z); a[5] = bfhi(wu.z); a[6] = bflo(wu.w); a[7] = bfhi(wu.w);
    }
    #pragma unroll 8
    for (int j = 0; j < 96; ++j) {
        float sj = seaL[i][h][j];
        float4 w0 = We4[j * 32 + 2 * p], w1 = We4[j * 32 + 2 * p + 1];
        a[0] += sj * w0.x; a[1] += sj * w0.y; a[2] += sj * w0.z; a[3] += sj * w0.w;
        a[4] += sj * w1.x; a[5] += sj * w1.y; a[6] += sj * w1.z; a[7] += sj * w1.w;
    }
    float4 sk0 = {0, 0, 0, 0}, sk1 = {0, 0, 0, 0};
    float dn = 0.f;
    if (n < N) {
        sk0 = ((const float4*)sbuf)[(size_t)n * 32 + 2 * p];
        sk1 = ((const float4*)sbuf)[(size_t)n * 32 + 2 * p + 1];
        dn = denb[(size_t)n * 2 + h];
    }
    float4 o0, o1;
    if (dn > 0.f) {
        const float r = 1.0f / dn;
        o0.x = a[0] * r + sk0.x; o0.y = a[1] * r + sk0.y;
        o0.z = a[2] * r + sk0.z; o0.w = a[3] * r + sk0.w;
        o1.x = a[4] * r + sk1.x; o1.y = a[5] * r + sk1.y;
        o1.z = a[6] * r + sk1.z; o1.w = a[7] * r + sk1.w;
    } else { o0 = sk0; o1 = sk1; }
    if (n < N) {
        ((float4*)outp)[(size_t)n * 32 + 2 * p] = o0;
        ((float4*)outp)[(size_t)n * 32 + 2 * p + 1] = o1;
    }

    if (do_bn) {
        if (n >= N) { o0 = make_float4(0,0,0,0); o1 = make_float4(0,0,0,0); }
        auto rs = [&](float x, int c) {
            x += __shfl_xor(x, 16); x += __shfl_xor(x, 32);
            if ((tid & 63) < 16) red[tid >> 6][tid & 15][c] = x;
        };
        rs(o0.x, 0); rs(o0.y, 1); rs(o0.z, 2); rs(o0.w, 3);
        rs(o1.x, 4); rs(o1.y, 5); rs(o1.z, 6); rs(o1.w, 7);
        rs(o0.x * o0.x, 8);  rs(o0.y * o0.y, 9);  rs(o0.z * o0.z, 10); rs(o0.w * o0.w, 11);
        rs(o1.x * o1.x, 12); rs(o1.y * o1.y, 13); rs(o1.z * o1.z, 14); rs(o1.w * o1.w, 15);
        __syncthreads();
        int pp = tid >> 4, cc = tid & 15;
        float tot = red[0][pp][cc] + red[1][pp][cc] + red[2][pp][cc] + red[3][pp][cc];
        int ch = pp * 8 + (cc & 7);
        if (cc < 8) atomicAdd(&bn_sum[ch], tot);
        else        atomicAdd(&bn_ssq[ch], tot);
    }
}

// ============ BN apply + ReLU (stats computed inline) -> bf16 ============
__global__ __launch_bounds__(256) void bn_apply_kernel(
    const float* __restrict__ pre, const float* __restrict__ bn_sum,
    const float* __restrict__ bn_ssq, const float* __restrict__ gw,
    const float* __restrict__ bw, ushort_t* __restrict__ xb,
    int N, size_t total)
{
    size_t i = (size_t)blockIdx.x * 256 + threadIdx.x;
    const size_t stride = (size_t)gridDim.x * 256;
    const float invN = 1.0f / (float)N;
    for (; i < total; i += stride) {
        int c = (int)(i & 127);
        float m = bn_sum[c] * invN;
        float var = fmaxf(bn_ssq[c] * invN - m * m, 0.f);
        float inv = rsqrtf(var + 1e-5f);
        float val = (pre[i] - m) * inv * gw[c] + bw[c];
        xb[i] = f2bf(fmaxf(val, 0.f));
    }
}

// =========================================================================
extern "C" void kernel_launch(void* const* d_in, const int* in_sizes, int n_in,
                              void* d_out, int out_size, void* d_ws, size_t ws_size,
                              hipStream_t stream)
{
    const float* x   = (const float*)d_in[0];
    const float* lu  = (const float*)d_in[1];
    const int*   ei  = (const int*)d_in[2];
    const float* t   = (const float*)d_in[3];
    const float* msg = (const float*)d_in[4];
    const float* tw  = (const float*)d_in[5];
    const float* tb  = (const float*)d_in[6];
    const float* bng = (const float*)d_in[7];
    const float* bnb = (const float*)d_in[8];
    const float* Wq1 = (const float*)d_in[9];  const float* bq1 = (const float*)d_in[10];
    const float* Wk1 = (const float*)d_in[11]; const float* bk1 = (const float*)d_in[12];
    const float* Wv1 = (const float*)d_in[13]; const float* bv1 = (const float*)d_in[14];
    const float* We1 = (const float*)d_in[15];
    const float* Ws1 = (const float*)d_in[16]; const float* bs1 = (const float*)d_in[17];
    const float* Wq2 = (const float*)d_in[18]; const float* bq2 = (const float*)d_in[19];
    const float* Wk2 = (const float*)d_in[20]; const float* bk2 = (const float*)d_in[21];
    const float* Wv2 = (const float*)d_in[22]; const float* bv2 = (const float*)d_in[23];
    const float* We2 = (const float*)d_in[24];
    const float* Ws2 = (const float*)d_in[25]; const float* bs2 = (const float*)d_in[26];

    const int N = in_sizes[0] / DD;
    const int E = in_sizes[3];
    const size_t NM = (size_t)N * DD;

    float* f   = (float*)d_ws;
    float* sb  = f;                          // NM floats
    float* pre = sb + NM;                    // NM floats
    uint_t* kvb = (uint_t*)(pre + NM);       // N*128 uints (k|v bf16)
    ushort_t* qbB = (ushort_t*)(kvb + (size_t)N * 128);  // N*128 ushorts (q bf16)
    ushort_t* ubB = qbB + (size_t)N * 128;   // N*256 ushorts (u bf16, 2 heads)
    ushort_t* xb  = ubB + (size_t)N * 256;   // N*128 ushorts (x bf16)
    uint_t* nodeAccB = (uint_t*)(xb + (size_t)N * 128);  // N*160 uints
    float* denb = (float*)(nodeAccB + (size_t)N * NA_STRIDE);  // N*2 floats
    ushort_t* wcat = (ushort_t*)(denb + (size_t)N * 2);  // 2*98304
    float* bcat = (float*)(wcat + 2 * 98304); // 2*768
    float* bsum = bcat + 2 * 768;             // 128
    float* bssq = bsum + 128;                 // 128
    int* cnt       = (int*)(bssq + 128);      // N
    int* row_start = cnt + N;                 // N+1
    int* cursor    = row_start + N + 1;       // N
    char* tail0 = (char*)(cursor + N);
    size_t off = (((size_t)(tail0 - (char*)d_ws)) + 255) & ~(size_t)255;

    int4*   ser  = (int4*)((char*)d_ws + off);                      // E
    uint_t* eaB2 = (uint_t*)((char*)d_ws + off + (size_t)E * 16);   // E*32
    size_t need_pre = off + (size_t)E * 16 + (size_t)E * 128 + 1024;
    const bool use_pre = (ws_size >= need_pre);

    const int EB = (E + 255) / 256;

    // ---- CSR + bf16 conversions + both layers' weight pack ----
    hipMemsetAsync(cnt, 0, (size_t)N * sizeof(int), stream);
    hist_kernel<<<EB, 256, 0, stream>>>(ei, cnt, E);
    scan_kernel<<<1, 1024, 0, stream>>>(cnt, row_start, cursor, N);
    scatter_fb_kernel<<<EB, 256, 0, stream>>>(ei, lu, t, cursor, ser, E);
    tobf_kernel<<<4096, 256, 0, stream>>>(
        (const float4*)msg, (uint2*)eaB2, use_pre ? (size_t)E * 16 : 0,
        (const float4*)x, (uint2*)xb, NM / 4);
    pack_w_kernel<<<dim3(384, 2), 256, 0, stream>>>(
        Wq1, Wk1, Wv1, Ws1, We1, bq1, bk1, bv1, bs1,
        Wq2, Wk2, Wv2, Ws2, We2, bq2, bk2, bv2, bs2, wcat, bcat);

    dim3 gemmGrid((N + 63) / 64, 6);
    const int attnGrid = (N + 7) / 8;
    const int finGrid = (N + 15) / 16;

    // ---------------- layer 1 ----------------
    mfma_gemm_kernel<<<gemmGrid, 256, 0, stream>>>(
        (const uint4*)xb, (const uint4*)wcat, bcat,
        qbB, (ushort_t*)kvb, sb, ubB, N);
    if (use_pre)
        node_attn_kernel<1><<<attnGrid, 256, 0, stream>>>(
            row_start, ser, eaB2, msg, tw, tb, qbB, kvb, ubB, nodeAccB, denb, N);
    else
        node_attn_kernel<0><<<attnGrid, 256, 0, stream>>>(
            row_start, ser, eaB2, msg, tw, tb, qbB, kvb, ubB, nodeAccB, denb, N);
    hipMemsetAsync(bsum, 0, 256 * sizeof(float), stream);
    ef_finish_kernel<<<finGrid, 256, 0, stream>>>(
        nodeAccB, denb, We1, sb, pre, bsum, bssq, N, 1);
    bn_apply_kernel<<<2048, 256, 0, stream>>>(pre, bsum, bssq, bng, bnb, xb, N, NM);

    // ---------------- layer 2 ----------------
    mfma_gemm_kernel<<<gemmGrid, 256, 0, stream>>>(
        (const uint4*)xb, (const uint4*)(wcat + 98304), bcat + 768,
        qbB, (ushort_t*)kvb, sb, ubB, N);
    if (use_pre)
        node_attn_kernel<1><<<attnGrid, 256, 0, stream>>>(
            row_start, ser, eaB2, msg, tw, tb, qbB, kvb, ubB, nodeAccB, denb, N);
    else
        node_attn_kernel<0><<<attnGrid, 256, 0, stream>>>(
            row_start, ser, eaB2, msg, tw, tb, qbB, kvb, ubB, nodeAccB, denb, N);
    ef_finish_kernel<<<finGrid, 256, 0, stream>>>(
        nodeAccB, denb, We2, sb, (float*)d_out, nullptr, nullptr, N, 0);
}

// Round 17
// 787.649 us; speedup vs baseline: 1.0223x; 1.0223x over previous
//
#include <hip/hip_runtime.h>
#include <math.h>

#define DD 128
typedef unsigned short ushort_t;
typedef unsigned int uint_t;
typedef __attribute__((ext_vector_type(8))) short bf16x8;
typedef __attribute__((ext_vector_type(4))) float f32x4;

// ---------------- DPP / bf16 helpers -------------------
template<int CTRL>
__device__ __forceinline__ float dppAdd(float x) {
    int y = __builtin_amdgcn_update_dpp(0, __float_as_int(x), CTRL, 0xF, 0xF, true);
    return x + __int_as_float(y);
}
__device__ __forceinline__ float red16(float x) {
    x = dppAdd<0xB1>(x);   // quad_perm xor1
    x = dppAdd<0x4E>(x);   // quad_perm xor2
    x = dppAdd<0x141>(x);  // row_half_mirror
    x = dppAdd<0x140>(x);  // row_mirror
    return x;
}

__device__ __forceinline__ ushort_t f2bf(float f) {
    uint_t u = __float_as_uint(f);
    u += 0x7FFFu + ((u >> 16) & 1u);
    return (ushort_t)(u >> 16);
}
__device__ __forceinline__ uint_t packbf(float a, float b) {
    return (uint_t)f2bf(a) | ((uint_t)f2bf(b) << 16);
}
__device__ __forceinline__ float bflo(uint_t u) { return __uint_as_float(u << 16); }
__device__ __forceinline__ float bfhi(uint_t u) { return __uint_as_float(u & 0xFFFF0000u); }

#define NA_STRIDE 160   // words/node: 64 (wv bf16) + 96 (sea bf16)

// ======================= CSR build (once per call) =======================
__global__ __launch_bounds__(256) void hist_kernel(const int* __restrict__ ei,
                                                   int* __restrict__ cnt, int E) {
    int i = blockIdx.x * 256 + threadIdx.x;
    if (i < E) atomicAdd(&cnt[ei[E + i]], 1);
}

__global__ __launch_bounds__(1024) void scan_kernel(const int* __restrict__ cnt,
                                                    int* __restrict__ row_start,
                                                    int* __restrict__ cursor, int N) {
    __shared__ int part[1024];
    const int tid = threadIdx.x;
    const int chunk = (N + 1023) >> 10;
    const int lo = min(N, tid * chunk);
    const int hi = min(N, lo + chunk);
    int s = 0;
    for (int i = lo; i < hi; ++i) s += cnt[i];
    part[tid] = s;
    __syncthreads();
    for (int off = 1; off < 1024; off <<= 1) {
        int val = 0;
        if (tid >= off) val = part[tid - off];
        __syncthreads();
        part[tid] += val;
        __syncthreads();
    }
    int run = (tid == 0) ? 0 : part[tid - 1];
    for (int i = lo; i < hi; ++i) {
        row_start[i] = run; cursor[i] = run;
        run += cnt[i];
    }
    if (tid == 1023) row_start[N] = part[1023];
}

// meta scatter: one int4 record per edge (src, eid, rel_bits, 0)
__global__ __launch_bounds__(256) void scatter_fb_kernel(
    const int* __restrict__ ei, const float* __restrict__ lu, const float* __restrict__ t,
    int* __restrict__ cursor, int4* __restrict__ ser, int E)
{
    int i = blockIdx.x * 256 + threadIdx.x;
    if (i < E) {
        int s = ei[i], d = ei[E + i];
        int pos = atomicAdd(&cursor[d], 1);
        ser[pos] = make_int4(s, i, __float_as_int(lu[s] - t[i]), 0);
    }
}

// fused streaming f32 -> bf16 for msg (n1 float4s) and x (n2 float4s)
__global__ __launch_bounds__(256) void tobf_kernel(
    const float4* __restrict__ a4, uint2* __restrict__ oa, size_t n1,
    const float4* __restrict__ b4, uint2* __restrict__ ob, size_t n2)
{
    size_t i = (size_t)blockIdx.x * 256 + threadIdx.x;
    const size_t stride = (size_t)gridDim.x * 256;
    const size_t total = n1 + n2;
    for (; i < total; i += stride) {
        if (i < n1) {
            float4 v = a4[i];
            oa[i] = make_uint2(packbf(v.x, v.y), packbf(v.z, v.w));
        } else {
            size_t j = i - n1;
            float4 v = b4[j];
            ob[j] = make_uint2(packbf(v.x, v.y), packbf(v.z, v.w));
        }
    }
}

// ====== pack 6 weight mats x 2 layers -> bf16 Wcat_t[2][768][128] ========
__global__ __launch_bounds__(256) void pack_w_kernel(
    const float* __restrict__ Wq1, const float* __restrict__ Wk1,
    const float* __restrict__ Wv1, const float* __restrict__ Wsk1,
    const float* __restrict__ We1,
    const float* __restrict__ bq1, const float* __restrict__ bk1,
    const float* __restrict__ bv1, const float* __restrict__ bsk1,
    const float* __restrict__ Wq2, const float* __restrict__ Wk2,
    const float* __restrict__ Wv2, const float* __restrict__ Wsk2,
    const float* __restrict__ We2,
    const float* __restrict__ bq2, const float* __restrict__ bk2,
    const float* __restrict__ bv2, const float* __restrict__ bsk2,
    ushort_t* __restrict__ wcat, float* __restrict__ bcat)
{
    const int layer = blockIdx.y;
    const float *Wq, *Wk, *Wv, *Wsk, *We, *bq, *bk, *bv, *bsk;
    if (layer == 0) { Wq=Wq1; Wk=Wk1; Wv=Wv1; Wsk=Wsk1; We=We1; bq=bq1; bk=bk1; bv=bv1; bsk=bsk1; }
    else            { Wq=Wq2; Wk=Wk2; Wv=Wv2; Wsk=Wsk2; We=We2; bq=bq2; bk=bk2; bv=bv2; bsk=bsk2; }

    int idx = blockIdx.x * 256 + threadIdx.x;   // [0, 98304)
    int cg = idx >> 7, k = idx & 127;
    int which = cg >> 7, col = cg & 127;
    float v = 0.f, b = 0.f;
    if (which < 4) {
        switch (which) {
            case 0:  v = Wq[k * 128 + col];  b = bq[col];  break;
            case 1:  v = Wk[k * 128 + col];  b = bk[col];  break;
            case 2:  v = Wv[k * 128 + col];  b = bv[col];  break;
            default: v = Wsk[k * 128 + col]; b = bsk[col]; break;
        }
    } else {
        const int h = which - 4;
        const int lh = col >> 3, j = col & 7;
        const int row = (j < 2) ? (2 * lh + j) : (j < 6 ? (32 + 4 * lh + (j - 2)) : -1);
        if (row >= 0) {
            const float* Wer = We + row * 128 + h * 64;
            const float* Wqr = Wq + k * 128 + h * 64;
            #pragma unroll 8
            for (int c = 0; c < 64; ++c) v += Wqr[c] * Wer[c];
            if (k == 0) {
                const float* bqr = bq + h * 64;
                #pragma unroll 8
                for (int c = 0; c < 64; ++c) b += bqr[c] * Wer[c];
            }
        }
    }
    wcat[(size_t)layer * 98304 + cg * 128 + k] = f2bf(v);
    if (k == 0) bcat[layer * 768 + cg] = b;
}

// ======================= MFMA 6-way node GEMM (bf16 in, K=128) ===========
// cb: 0=q(bf16) 1=k(bf16,interleaved kv) 2=v(bf16,interleaved kv)
//     3=skip(f32) 4=u0(bf16) 5=u1(bf16)
// kv row layout: slot l (uint4) = {k[4l..4l+3], v[4l..4l+3]}
__global__ __launch_bounds__(256) void mfma_gemm_kernel(
    const uint4* __restrict__ xb4,   // [M][16] uint4 (128 bf16/row)
    const uint4* __restrict__ wc4,   // [768][16]
    const float* __restrict__ bcat,  // [768]
    ushort_t* __restrict__ qbB, ushort_t* __restrict__ kvbS,
    float* __restrict__ sb, ushort_t* __restrict__ ubB, int M)
{
    __shared__ ushort_t Xs[64 * 136];
    __shared__ ushort_t Wt[128 * 136];
    const int tid = threadIdx.x;
    const int m0 = blockIdx.x * 64;
    const int cb = blockIdx.y;

    #pragma unroll
    for (int i = 0; i < 4; ++i) {
        int f = tid + i * 256, r = f >> 4, ch = f & 15;
        uint4 val = make_uint4(0, 0, 0, 0);
        if (m0 + r < M) val = xb4[(size_t)(m0 + r) * 16 + ch];
        *(uint4*)&Xs[r * 136 + ch * 8] = val;
    }
    #pragma unroll
    for (int i = 0; i < 8; ++i) {
        int f = tid + i * 256, r = f >> 4, ch = f & 15;
        *(uint4*)&Wt[r * 136 + ch * 8] = wc4[(size_t)(cb * 128 + r) * 16 + ch];
    }
    __syncthreads();

    const int w = tid >> 6, l = tid & 63, rl = l & 15, g = l >> 4;
    f32x4 acc[8];
    #pragma unroll
    for (int c = 0; c < 8; ++c) acc[c] = (f32x4){0.f, 0.f, 0.f, 0.f};
    const ushort_t* Ar = &Xs[(w * 16 + rl) * 136];
    #pragma unroll
    for (int kk = 0; kk < 4; ++kk) {
        bf16x8 a = *(const bf16x8*)&Ar[kk * 32 + g * 8];
        #pragma unroll
        for (int c = 0; c < 8; ++c) {
            bf16x8 b = *(const bf16x8*)&Wt[(c * 16 + rl) * 136 + kk * 32 + g * 8];
            acc[c] = __builtin_amdgcn_mfma_f32_16x16x32_bf16(a, b, acc[c], 0, 0, 0);
        }
    }
    float bias_c[8];
    #pragma unroll
    for (int c = 0; c < 8; ++c) bias_c[c] = bcat[cb * 128 + c * 16 + rl];

    const int R0 = m0 + w * 16 + g * 4;
    #pragma unroll
    for (int r = 0; r < 4; ++r) {
        int R = R0 + r;
        if (R < M) {
            if (cb == 3) {
                #pragma unroll
                for (int c = 0; c < 8; ++c)
                    sb[(size_t)R * 128 + c * 16 + rl] = acc[c][r] + bias_c[c];
            } else if (cb == 1 || cb == 2) {
                const int kvoff = (cb == 2) ? 4 : 0;   // v goes to back half of slot
                #pragma unroll
                for (int c = 0; c < 8; ++c) {
                    int ch = c * 16 + rl;
                    kvbS[(size_t)R * 256 + ((ch >> 2) << 3) + kvoff + (ch & 3)] =
                        f2bf(acc[c][r] + bias_c[c]);
                }
            } else {
                ushort_t* bp; int bstride, boff;
                if (cb == 0) { bp = qbB; bstride = 128; boff = 0; }
                else if (cb == 4) { bp = ubB; bstride = 256; boff = 0; }
                else { bp = ubB; bstride = 256; boff = 128; }
                #pragma unroll
                for (int c = 0; c < 8; ++c)
                    bp[(size_t)R * bstride + boff + c * 16 + rl] = f2bf(acc[c][r] + bias_c[c]);
            }
        }
    }
}

// ======================= node-centric attention ==========================
// Two-chunk pipeline; k+v fetched as ONE dwordx4 per edge/lane (interleaved).
template<int PRE>
__global__ __launch_bounds__(256) void node_attn_kernel(
    const int* __restrict__ row_start, const int4* __restrict__ ser,
    const uint_t* __restrict__ eaB,
    const float* __restrict__ msg,
    const float* __restrict__ time_w, const float* __restrict__ time_b,
    const ushort_t* __restrict__ qbB, const uint_t* __restrict__ kvb,
    const ushort_t* __restrict__ ubB, uint_t* __restrict__ nodeAccB,
    float* __restrict__ denb, int N)
{
    const int tid = threadIdx.x;
    const int g = tid >> 5, l = tid & 31;
    const int lh = l & 15;
    const int h = l >> 4;
    const int n = blockIdx.x * 8 + g;
    if (n >= N) return;

    const float twA = time_w[2 * lh], twB = time_w[2 * lh + 1];
    const float tbA = time_b[2 * lh], tbB = time_b[2 * lh + 1];
    const int e0 = row_start[n], e1 = row_start[n + 1];
    const uint2 qa = ((const uint2*)qbB)[(size_t)n * 32 + l];
    const float qx = bflo(qa.x), qy = bfhi(qa.x);
    const float qz = bflo(qa.y), qw = bfhi(qa.y);
    const uint4 ua = ((const uint4*)ubB)[(size_t)n * 32 + h * 16 + lh];
    const float uu0 = bflo(ua.x), uu1 = bfhi(ua.x);
    const float uu2 = bflo(ua.y), uu3 = bfhi(ua.y);
    const float uu4 = bflo(ua.z), uu5 = bfhi(ua.z);
    const uint4* KV4 = (const uint4*)kvb;
    const uint2* EB2 = (const uint2*)eaB;

    float4 wv = {0, 0, 0, 0};
    float sA = 0, sB = 0, s0 = 0, s1 = 0, s2 = 0, s3 = 0, denA = 0;

    struct Ch { int src[4]; float rel[4]; uint2 eb[4]; float4 mf[4]; uint4 kv[4]; };
    Ch cur, nxt;

    auto LOAD_META = [&](Ch& c, int b) {
        #pragma unroll
        for (int j = 0; j < 4; ++j) {
            int idx = b + j; idx = idx < e1 ? idx : e1 - 1;
            int4 m = ser[idx];
            c.src[j] = m.x;
            c.rel[j] = __int_as_float(m.z);
            if (PRE) c.eb[j] = EB2[(size_t)m.y * 16 + lh];
            else     c.mf[j] = ((const float4*)msg)[(size_t)m.y * 16 + lh];
        }
    };
    auto LOAD_GATHER = [&](Ch& c) {
        #pragma unroll
        for (int j = 0; j < 4; ++j)
            c.kv[j] = KV4[(size_t)c.src[j] * 32 + l];
    };
    auto PROCESS = [&](Ch& c, int b) {
        #pragma unroll
        for (int j = 0; j < 4; ++j) {
            float cA = __cosf(c.rel[j] * twA + tbA);
            float cB = __cosf(c.rel[j] * twB + tbB);
            float m0, m1, m2, m3;
            if (PRE) {
                m0 = bflo(c.eb[j].x); m1 = bfhi(c.eb[j].x);
                m2 = bflo(c.eb[j].y); m3 = bfhi(c.eb[j].y);
            } else {
                m0 = c.mf[j].x; m1 = c.mf[j].y; m2 = c.mf[j].z; m3 = c.mf[j].w;
            }
            float k0 = bflo(c.kv[j].x), k1 = bfhi(c.kv[j].x);
            float k2 = bflo(c.kv[j].y), k3 = bfhi(c.kv[j].y);
            float p = qx * k0 + qy * k1 + qz * k2 + qw * k3
                    + cA * uu0 + cB * uu1 + m0 * uu2 + m1 * uu3
                    + m2 * uu4 + m3 * uu5;
            p = red16(p);
            float w = __expf(p * 0.125f);
            if (b + j >= e1) w = 0.f;
            denA += w;
            float v0 = bflo(c.kv[j].z), v1 = bfhi(c.kv[j].z);
            float v2 = bflo(c.kv[j].w), v3 = bfhi(c.kv[j].w);
            wv.x += w * v0; wv.y += w * v1; wv.z += w * v2; wv.w += w * v3;
            sA += w * cA; sB += w * cB;
            s0 += w * m0; s1 += w * m1; s2 += w * m2; s3 += w * m3;
        }
    };

    if (e0 < e1) {
        LOAD_META(cur, e0);
        LOAD_GATHER(cur);
        for (int base = e0; base < e1; base += 4) {
            const bool more = (base + 4) < e1;
            if (more) LOAD_META(nxt, base + 4);
            PROCESS(cur, base);
            if (more) { LOAD_GATHER(nxt); cur = nxt; }
        }
    }
    // note: wv holds v channels 4l..4l+3 -> write to channel block 4l
    uint_t* NB = nodeAccB + (size_t)n * NA_STRIDE;
    NB[2 * l]     = packbf(wv.x, wv.y);
    NB[2 * l + 1] = packbf(wv.z, wv.w);
    NB[64 + 3 * l]     = packbf(sA, sB);
    NB[64 + 3 * l + 1] = packbf(s0, s1);
    NB[64 + 3 * l + 2] = packbf(s2, s3);
    if (lh == 0) denb[(size_t)n * 2 + h] = denA;
}

// ======================= node finish: out = (wv + sea@We)/den + skip =====
__global__ __launch_bounds__(256) void ef_finish_kernel(
    const uint_t* __restrict__ nodeAccB, const float* __restrict__ denb,
    const float* __restrict__ We,
    const float* __restrict__ sbuf, float* __restrict__ outp,
    float* __restrict__ bn_sum, float* __restrict__ bn_ssq, int N, int do_bn)
{
    __shared__ float seaL[16][2][100];
    __shared__ float red[4][16][16];
    const int tid = threadIdx.x;
    const int n0 = blockIdx.x * 16;

    #pragma unroll
    for (int it = 0; it < 6; ++it) {
        int f = tid + it * 256;
        int i2 = f / 96, wi = f - i2 * 96;
        if (n0 + i2 < N) {
            uint_t uv = nodeAccB[(size_t)(n0 + i2) * NA_STRIDE + 64 + wi];
            int L = wi / 3, k = wi - L * 3;
            int h2 = L >> 4, lh2 = L & 15;
            float lo = bflo(uv), hi = bfhi(uv);
            if (k == 0)      { seaL[i2][h2][2 * lh2] = lo;         seaL[i2][h2][2 * lh2 + 1] = hi; }
            else if (k == 1) { seaL[i2][h2][32 + 4 * lh2] = lo;    seaL[i2][h2][32 + 4 * lh2 + 1] = hi; }
            else             { seaL[i2][h2][32 + 4 * lh2 + 2] = lo; seaL[i2][h2][32 + 4 * lh2 + 3] = hi; }
        }
    }
    __syncthreads();

    const int i = tid >> 4, p = tid & 15, h = p >> 3;
    const int n = n0 + i;
    const float4* We4 = (const float4*)We;
    float a[8] = {0, 0, 0, 0, 0, 0, 0, 0};
    if (n < N) {
        uint4 wu = *(const uint4*)&nodeAccB[(size_t)n * NA_STRIDE + 4 * p];
        a[0] = bflo(wu.x); a[1] = bfhi(wu.x); a[2] = bflo(wu.y); a[3] = bfhi(wu.y);
        a[4] = bflo(wu.z); a[5] = bfhi(wu.z); a[6] = bflo(wu.w); a[7] = bfhi(wu.w);
    }
    #pragma unroll 8
    for (int j = 0; j < 96; ++j) {
        float sj = seaL[i][h][j];
        float4 w0 = We4[j * 32 + 2 * p], w1 = We4[j * 32 + 2 * p + 1];
        a[0] += sj * w0.x; a[1] += sj * w0.y; a[2] += sj * w0.z; a[3] += sj * w0.w;
        a[4] += sj * w1.x; a[5] += sj * w1.y; a[6] += sj * w1.z; a[7] += sj * w1.w;
    }
    float4 sk0 = {0, 0, 0, 0}, sk1 = {0, 0, 0, 0};
    float dn = 0.f;
    if (n < N) {
        sk0 = ((const float4*)sbuf)[(size_t)n * 32 + 2 * p];
        sk1 = ((const float4*)sbuf)[(size_t)n * 32 + 2 * p + 1];
        dn = denb[(size_t)n * 2 + h];
    }
    float4 o0, o1;
    if (dn > 0.f) {
        const float r = 1.0f / dn;
        o0.x = a[0] * r + sk0.x; o0.y = a[1] * r + sk0.y;
        o0.z = a[2] * r + sk0.z; o0.w = a[3] * r + sk0.w;
        o1.x = a[4] * r + sk1.x; o1.y = a[5] * r + sk1.y;
        o1.z = a[6] * r + sk1.z; o1.w = a[7] * r + sk1.w;
    } else { o0 = sk0; o1 = sk1; }
    if (n < N) {
        ((float4*)outp)[(size_t)n * 32 + 2 * p] = o0;
        ((float4*)outp)[(size_t)n * 32 + 2 * p + 1] = o1;
    }

    if (do_bn) {
        if (n >= N) { o0 = make_float4(0,0,0,0); o1 = make_float4(0,0,0,0); }
        auto rs = [&](float x, int c) {
            x += __shfl_xor(x, 16); x += __shfl_xor(x, 32);
            if ((tid & 63) < 16) red[tid >> 6][tid & 15][c] = x;
        };
        rs(o0.x, 0); rs(o0.y, 1); rs(o0.z, 2); rs(o0.w, 3);
        rs(o1.x, 4); rs(o1.y, 5); rs(o1.z, 6); rs(o1.w, 7);
        rs(o0.x * o0.x, 8);  rs(o0.y * o0.y, 9);  rs(o0.z * o0.z, 10); rs(o0.w * o0.w, 11);
        rs(o1.x * o1.x, 12); rs(o1.y * o1.y, 13); rs(o1.z * o1.z, 14); rs(o1.w * o1.w, 15);
        __syncthreads();
        int pp = tid >> 4, cc = tid & 15;
        float tot = red[0][pp][cc] + red[1][pp][cc] + red[2][pp][cc] + red[3][pp][cc];
        int ch = pp * 8 + (cc & 7);
        if (cc < 8) atomicAdd(&bn_sum[ch], tot);
        else        atomicAdd(&bn_ssq[ch], tot);
    }
}

// ============ BN apply + ReLU (stats computed inline) -> bf16 ============
__global__ __launch_bounds__(256) void bn_apply_kernel(
    const float* __restrict__ pre, const float* __restrict__ bn_sum,
    const float* __restrict__ bn_ssq, const float* __restrict__ gw,
    const float* __restrict__ bw, ushort_t* __restrict__ xb,
    int N, size_t total)
{
    size_t i = (size_t)blockIdx.x * 256 + threadIdx.x;
    const size_t stride = (size_t)gridDim.x * 256;
    const float invN = 1.0f / (float)N;
    for (; i < total; i += stride) {
        int c = (int)(i & 127);
        float m = bn_sum[c] * invN;
        float var = fmaxf(bn_ssq[c] * invN - m * m, 0.f);
        float inv = rsqrtf(var + 1e-5f);
        float val = (pre[i] - m) * inv * gw[c] + bw[c];
        xb[i] = f2bf(fmaxf(val, 0.f));
    }
}

// =========================================================================
extern "C" void kernel_launch(void* const* d_in, const int* in_sizes, int n_in,
                              void* d_out, int out_size, void* d_ws, size_t ws_size,
                              hipStream_t stream)
{
    const float* x   = (const float*)d_in[0];
    const float* lu  = (const float*)d_in[1];
    const int*   ei  = (const int*)d_in[2];
    const float* t   = (const float*)d_in[3];
    const float* msg = (const float*)d_in[4];
    const float* tw  = (const float*)d_in[5];
    const float* tb  = (const float*)d_in[6];
    const float* bng = (const float*)d_in[7];
    const float* bnb = (const float*)d_in[8];
    const float* Wq1 = (const float*)d_in[9];  const float* bq1 = (const float*)d_in[10];
    const float* Wk1 = (const float*)d_in[11]; const float* bk1 = (const float*)d_in[12];
    const float* Wv1 = (const float*)d_in[13]; const float* bv1 = (const float*)d_in[14];
    const float* We1 = (const float*)d_in[15];
    const float* Ws1 = (const float*)d_in[16]; const float* bs1 = (const float*)d_in[17];
    const float* Wq2 = (const float*)d_in[18]; const float* bq2 = (const float*)d_in[19];
    const float* Wk2 = (const float*)d_in[20]; const float* bk2 = (const float*)d_in[21];
    const float* Wv2 = (const float*)d_in[22]; const float* bv2 = (const float*)d_in[23];
    const float* We2 = (const float*)d_in[24];
    const float* Ws2 = (const float*)d_in[25]; const float* bs2 = (const float*)d_in[26];

    const int N = in_sizes[0] / DD;
    const int E = in_sizes[3];
    const size_t NM = (size_t)N * DD;

    float* f   = (float*)d_ws;
    float* sb  = f;                          // NM floats
    float* pre = sb + NM;                    // NM floats
    uint_t* kvb = (uint_t*)(pre + NM);       // N*128 uints (interleaved k|v bf16)
    ushort_t* qbB = (ushort_t*)(kvb + (size_t)N * 128);  // N*128 ushorts (q bf16)
    ushort_t* ubB = qbB + (size_t)N * 128;   // N*256 ushorts (u bf16, 2 heads)
    ushort_t* xb  = ubB + (size_t)N * 256;   // N*128 ushorts (x bf16)
    uint_t* nodeAccB = (uint_t*)(xb + (size_t)N * 128);  // N*160 uints
    float* denb = (float*)(nodeAccB + (size_t)N * NA_STRIDE);  // N*2 floats
    ushort_t* wcat = (ushort_t*)(denb + (size_t)N * 2);  // 2*98304
    float* bcat = (float*)(wcat + 2 * 98304); // 2*768
    float* bsum = bcat + 2 * 768;             // 128
    float* bssq = bsum + 128;                 // 128
    int* cnt       = (int*)(bssq + 128);      // N
    int* row_start = cnt + N;                 // N+1
    int* cursor    = row_start + N + 1;       // N
    char* tail0 = (char*)(cursor + N);
    size_t off = (((size_t)(tail0 - (char*)d_ws)) + 255) & ~(size_t)255;

    int4*   ser  = (int4*)((char*)d_ws + off);                      // E
    uint_t* eaB2 = (uint_t*)((char*)d_ws + off + (size_t)E * 16);   // E*32
    size_t need_pre = off + (size_t)E * 16 + (size_t)E * 128 + 1024;
    const bool use_pre = (ws_size >= need_pre);

    const int EB = (E + 255) / 256;

    // ---- CSR + bf16 conversions + both layers' weight pack ----
    hipMemsetAsync(cnt, 0, (size_t)N * sizeof(int), stream);
    hist_kernel<<<EB, 256, 0, stream>>>(ei, cnt, E);
    scan_kernel<<<1, 1024, 0, stream>>>(cnt, row_start, cursor, N);
    scatter_fb_kernel<<<EB, 256, 0, stream>>>(ei, lu, t, cursor, ser, E);
    tobf_kernel<<<4096, 256, 0, stream>>>(
        (const float4*)msg, (uint2*)eaB2, use_pre ? (size_t)E * 16 : 0,
        (const float4*)x, (uint2*)xb, NM / 4);
    pack_w_kernel<<<dim3(384, 2), 256, 0, stream>>>(
        Wq1, Wk1, Wv1, Ws1, We1, bq1, bk1, bv1, bs1,
        Wq2, Wk2, Wv2, Ws2, We2, bq2, bk2, bv2, bs2, wcat, bcat);

    dim3 gemmGrid((N + 63) / 64, 6);
    const int attnGrid = (N + 7) / 8;
    const int finGrid = (N + 15) / 16;

    // ---------------- layer 1 ----------------
    mfma_gemm_kernel<<<gemmGrid, 256, 0, stream>>>(
        (const uint4*)xb, (const uint4*)wcat, bcat,
        qbB, (ushort_t*)kvb, sb, ubB, N);
    if (use_pre)
        node_attn_kernel<1><<<attnGrid, 256, 0, stream>>>(
            row_start, ser, eaB2, msg, tw, tb, qbB, kvb, ubB, nodeAccB, denb, N);
    else
        node_attn_kernel<0><<<attnGrid, 256, 0, stream>>>(
            row_start, ser, eaB2, msg, tw, tb, qbB, kvb, ubB, nodeAccB, denb, N);
    hipMemsetAsync(bsum, 0, 256 * sizeof(float), stream);
    ef_finish_kernel<<<finGrid, 256, 0, stream>>>(
        nodeAccB, denb, We1, sb, pre, bsum, bssq, N, 1);
    bn_apply_kernel<<<2048, 256, 0, stream>>>(pre, bsum, bssq, bng, bnb, xb, N, NM);

    // ---------------- layer 2 ----------------
    mfma_gemm_kernel<<<gemmGrid, 256, 0, stream>>>(
        (const uint4*)xb, (const uint4*)(wcat + 98304), bcat + 768,
        qbB, (ushort_t*)kvb, sb, ubB, N);
    if (use_pre)
        node_attn_kernel<1><<<attnGrid, 256, 0, stream>>>(
            row_start, ser, eaB2, msg, tw, tb, qbB, kvb, ubB, nodeAccB, denb, N);
    else
        node_attn_kernel<0><<<attnGrid, 256, 0, stream>>>(
            row_start, ser, eaB2, msg, tw, tb, qbB, kvb, ubB, nodeAccB, denb, N);
    ef_finish_kernel<<<finGrid, 256, 0, stream>>>(
        nodeAccB, denb, We2, sb, (float*)d_out, nullptr, nullptr, N, 0);
}